// Round 6
// baseline (434.753 us; speedup 1.0000x reference)
//
#include <hip/hip_runtime.h>

typedef unsigned short u16;
typedef __bf16 bf16x8 __attribute__((ext_vector_type(8)));
typedef float floatx4 __attribute__((ext_vector_type(4)));

#define B_ 4
#define SEQ 2048
#define DIM 1024

__device__ __forceinline__ u16 f2bf(float f) {
    unsigned u = __builtin_bit_cast(unsigned, f);
    u += 0x7FFFu + ((u >> 16) & 1u);
    return (u16)(u >> 16);
}
__device__ __forceinline__ float bf2f(u16 h) {
    unsigned u = ((unsigned)h) << 16;
    return __builtin_bit_cast(float, u);
}

#define GPTR(p) ((const __attribute__((address_space(1))) void*)(p))
#define LPTR(p) ((__attribute__((address_space(3))) void*)(p))
#define GLD(src, dstp) __builtin_amdgcn_global_load_lds(GPTR(src), LPTR(dstp), 16, 0, 0)

// ------------- prep: convert x fp32->bf16  +  transpose W fp32->Wt bf16 -----
// Fused (independent work): blocks [0,8192) convert, [8192,8960) transpose.
__global__ __launch_bounds__(256) void prep(
    const float4* __restrict__ x, ushort4* __restrict__ xb,
    const float* __restrict__ Wq, const float* __restrict__ Wk,
    const float* __restrict__ Wv, u16* __restrict__ Wt) {
    const int bx = blockIdx.x, tid = threadIdx.x;
    if (bx < 8192) {
        int i = bx * 256 + tid;  // 2M float4s
        float4 v = x[i];
        ushort4 o;
        o.x = f2bf(v.x); o.y = f2bf(v.y); o.z = f2bf(v.z); o.w = f2bf(v.w);
        xb[i] = o;
        return;
    }
    __shared__ u16 t[64][66];
    const int b = bx - 8192;               // 0..767
    const int kx = b & 15, ny = (b >> 4) & 15, z = b >> 8;
    const float* W = (z == 0) ? Wq : ((z == 1) ? Wk : Wv);
    u16* out = Wt + (size_t)z * DIM * DIM;
    const int tx = tid & 31, ty = tid >> 5;   // (32,8)
    const int k0 = kx * 64, n0 = ny * 64;
#pragma unroll
    for (int j = 0; j < 8; j++) {
        int k = ty + 8 * j;
        float2 v = *(const float2*)(W + (size_t)(k0 + k) * DIM + n0 + 2 * tx);
        t[2 * tx][k] = f2bf(v.x);
        t[2 * tx + 1][k] = f2bf(v.y);
    }
    __syncthreads();
#pragma unroll
    for (int j = 0; j < 8; j++) {
        int n = ty + 8 * j;
        ushort2 o;
        o.x = t[n][2 * tx];
        o.y = t[n][2 * tx + 1];
        *(ushort2*)(out + (size_t)(n0 + n) * DIM + k0 + 2 * tx) = o;
    }
}

// ---- 128x128 bf16 MFMA mainloop (used by scores/pv) -----------------------
__device__ __forceinline__ void mainloop(
    const u16* __restrict__ Ab, const u16* __restrict__ Bb, int lda, int ldb,
    int Kt, u16* lsA, u16* lsB, int tid, int wave, int quad, int l15,
    int wm, int wn, floatx4 (&acc)[4][4]) {
    const int srow = tid >> 2;                                // 0..63
    const int scol = ((tid & 3) ^ ((tid >> 3) & 3)) * 8;      // swizzled kseg
    const u16* gA = Ab + (size_t)srow * lda + scol;
    const u16* gB = Bb + (size_t)srow * ldb + scol;
    const int swq = (quad ^ ((l15 >> 1) & 3)) * 8;            // read-side xor

#pragma unroll
    for (int i = 0; i < 4; i++)
#pragma unroll
        for (int j = 0; j < 4; j++) {
            floatx4 zz = {0.f, 0.f, 0.f, 0.f};
            acc[i][j] = zz;
        }

    for (int k0 = 0; k0 < Kt; k0 += 64) {
#pragma unroll
        for (int h = 0; h < 2; h++)
#pragma unroll
            for (int c = 0; c < 2; c++) {
                __builtin_amdgcn_global_load_lds(
                    GPTR(gA + (size_t)c * 64 * lda + h * 32),
                    LPTR(lsA + h * 4096 + c * 2048 + wave * 512), 16, 0, 0);
                __builtin_amdgcn_global_load_lds(
                    GPTR(gB + (size_t)c * 64 * ldb + h * 32),
                    LPTR(lsB + h * 4096 + c * 2048 + wave * 512), 16, 0, 0);
            }
        gA += 64; gB += 64;
        __syncthreads();

#pragma unroll
        for (int h = 0; h < 2; h++) {
            bf16x8 af[4];
#pragma unroll
            for (int i = 0; i < 4; i++)
                af[i] = *(const bf16x8*)(lsA + h * 4096 + (wm + i * 16 + l15) * 32 + swq);
#pragma unroll
            for (int j = 0; j < 4; j++) {
                bf16x8 bfr = *(const bf16x8*)(lsB + h * 4096 + (wn + j * 16 + l15) * 32 + swq);
#pragma unroll
                for (int i = 0; i < 4; i++)
                    acc[i][j] = __builtin_amdgcn_mfma_f32_16x16x32_bf16(af[i], bfr, acc[i][j], 0, 0, 0);
            }
        }
        __syncthreads();
    }
}

// ========== QKV projection: 128x256 tile, BK=64, ring-3 LDS, 1 barrier/tile =
// (verified rounds 3+4: 63-64 µs, MfmaUtil 33%, no spill) — r3 verbatim.
__global__ __launch_bounds__(512, 2) void gemm_qkv_r3(
    const u16* __restrict__ A, const u16* __restrict__ Bt, u16* __restrict__ QK,
    const float* __restrict__ b0, const float* __restrict__ b1,
    const float* __restrict__ b2, u16* __restrict__ VtOut) {
    __shared__ union {
        u16 stage[3][24576];   // 3 x (A 16KB + B 32KB) = 144 KiB
        u16 T[256 * 128];      // V^T transpose staging (64 KB)
    } sm;

    const int tid = threadIdx.x;
    const int wave = tid >> 6, lane = tid & 63;
    const int quad = lane >> 4, l15 = lane & 15;
    const int wm = (wave >> 2) * 64;   // 2 M-waves
    const int wn = (wave & 3) * 64;    // 4 N-waves
    const int wl = wave * 512;         // wave-uniform LDS chunk (u16)

    // XCD-bijective swizzle: 768 = 8 * 96; mt-fast (B-panel L2 reuse)
    const int bid = blockIdx.x;
    const int wgid = (bid & 7) * 96 + (bid >> 3);
    const int mt = wgid & 63, nt = wgid >> 6;   // 64 M-tiles x 12 N-tiles

    // staging: thread t covers row t>>3 (of 64), slot t&7; src seg pre-swizzled
    const int srow = tid >> 3;
    const int sseg = (tid & 7) ^ (srow & 7);
    const u16* gA = A + (size_t)(mt * 128 + srow) * DIM + sseg * 8;
    const u16* gB = Bt + (size_t)(nt * 256 + srow) * DIM + sseg * 8;

    u16* p0 = &sm.stage[0][0];
    u16* p1 = &sm.stage[1][0];
    u16* p2 = &sm.stage[2][0];

    const int s0 = (quad ^ (l15 & 7)) * 8;      // ks=0 slot; ks=1 = s0 ^ 32
    const int rAoff = (wm + l15) * 64;
    const int rBoff = 8192 + (wn + l15) * 64;

    floatx4 acc[4][4];
#pragma unroll
    for (int i = 0; i < 4; i++)
#pragma unroll
        for (int j = 0; j < 4; j++) {
            floatx4 zz = {0.f, 0.f, 0.f, 0.f};
            acc[i][j] = zz;
        }

#define QKV_STAGE(bW) do { \
    GLD(gA,                      (bW) + wl); \
    GLD(gA + (size_t)64 * DIM,   (bW) + 4096 + wl); \
    GLD(gB,                      (bW) + 8192 + wl); \
    GLD(gB + (size_t)64 * DIM,   (bW) + 12288 + wl); \
    GLD(gB + (size_t)128 * DIM,  (bW) + 16384 + wl); \
    GLD(gB + (size_t)192 * DIM,  (bW) + 20480 + wl); \
    gA += 64; gB += 64; } while (0)

#define QKV_TILE(bR, bW, STG, EVM) do { \
    __builtin_amdgcn_s_barrier(); \
    if (STG) QKV_STAGE(bW); \
    const u16* rA_ = (bR) + rAoff; \
    const u16* rB_ = (bR) + rBoff; \
    bf16x8 a_[4], bv_[4]; \
    _Pragma("unroll") for (int i_ = 0; i_ < 4; ++i_) a_[i_] = *(const bf16x8*)(rA_ + i_ * 1024 + s0); \
    _Pragma("unroll") for (int j_ = 0; j_ < 4; ++j_) bv_[j_] = *(const bf16x8*)(rB_ + j_ * 1024 + s0); \
    __builtin_amdgcn_s_setprio(1); \
    _Pragma("unroll") for (int j_ = 0; j_ < 4; ++j_) \
    _Pragma("unroll") for (int i_ = 0; i_ < 4; ++i_) \
        acc[i_][j_] = __builtin_amdgcn_mfma_f32_16x16x32_bf16(a_[i_], bv_[j_], acc[i_][j_], 0, 0, 0); \
    __builtin_amdgcn_s_setprio(0); \
    _Pragma("unroll") for (int i_ = 0; i_ < 4; ++i_) a_[i_] = *(const bf16x8*)(rA_ + i_ * 1024 + (s0 ^ 32)); \
    _Pragma("unroll") for (int j_ = 0; j_ < 4; ++j_) bv_[j_] = *(const bf16x8*)(rB_ + j_ * 1024 + (s0 ^ 32)); \
    __builtin_amdgcn_s_setprio(1); \
    _Pragma("unroll") for (int j_ = 0; j_ < 4; ++j_) \
    _Pragma("unroll") for (int i_ = 0; i_ < 4; ++i_) \
        acc[i_][j_] = __builtin_amdgcn_mfma_f32_16x16x32_bf16(a_[i_], bv_[j_], acc[i_][j_], 0, 0, 0); \
    __builtin_amdgcn_s_setprio(0); \
    if ((EVM) == 6) { asm volatile("s_waitcnt vmcnt(6)" ::: "memory"); } \
    else if ((EVM) == 0) { asm volatile("s_waitcnt vmcnt(0)" ::: "memory"); } \
    } while (0)

    // prologue: stage tiles 0,1; force tile 0 landed (6 newest = tile 1 float)
    QKV_STAGE(p0);
    QKV_STAGE(p1);
    asm volatile("s_waitcnt vmcnt(6)" ::: "memory");

    for (int tt = 0; tt < 4; ++tt) {   // T = 0..11
        QKV_TILE(p0, p2, 1, 6);
        QKV_TILE(p1, p0, 1, 6);
        QKV_TILE(p2, p1, 1, 6);
    }
    QKV_TILE(p0, p2, 1, 6);    // T=12 (stages tile 14)
    QKV_TILE(p1, p0, 1, 6);    // T=13 (stages tile 15; forces 14)
    QKV_TILE(p2, p1, 0, 0);    // T=14 (tail drain: forces 15)
    QKV_TILE(p0, p1, 0, -1);   // T=15

#undef QKV_TILE
#undef QKV_STAGE

    // ---------------- epilogue ----------------
    const int z = nt >> 2;                          // 0=Q 1=K 2=V
    const int nc = (nt & 3) * 256 + wn + l15;       // col within z-matrix (+j*16)
    const float* bias = (z == 0) ? b0 : ((z == 1) ? b1 : b2);

    if (z < 2) {
        u16* Cb = QK + (size_t)z * B_ * SEQ * DIM;
        const int m00 = mt * 128 + wm + quad * 4;
#pragma unroll
        for (int j = 0; j < 4; ++j) {
            float bv2 = bias[nc + j * 16];
#pragma unroll
            for (int i = 0; i < 4; ++i)
#pragma unroll
                for (int r = 0; r < 4; ++r)
                    Cb[(size_t)(m00 + i * 16 + r) * DIM + nc + j * 16] =
                        f2bf(acc[i][j][r] + bv2);
        }
        return;
    }

    // z == 2: V^T [d][s] via LDS transpose (token-XOR swizzle kills the
    // 256B-stride conflict; XOR in 8-token units keeps 8B writes/16B reads ok)
    float addj[4];
#pragma unroll
    for (int j = 0; j < 4; ++j) addj[j] = bias[nc + j * 16];
    __syncthreads();                 // all waves done with stage LDS
#pragma unroll
    for (int i = 0; i < 4; ++i) {
        const int tb = wm + i * 16 + quad * 4;       // token base 0..127 (x4)
#pragma unroll
        for (int j = 0; j < 4; ++j) {
            const int d = wn + j * 16 + l15;         // local dim 0..255
            ushort4 o;
            o.x = f2bf(acc[i][j][0] + addj[j]);
            o.y = f2bf(acc[i][j][1] + addj[j]);
            o.z = f2bf(acc[i][j][2] + addj[j]);
            o.w = f2bf(acc[i][j][3] + addj[j]);
            *(ushort4*)&sm.T[d * 128 + (tb ^ ((d & 7) << 3))] = o;
        }
    }
    __syncthreads();
    const int bI = mt >> 4;
    const int sbase = (mt & 15) * 128;
    u16* Vb = VtOut + (size_t)bI * DIM * SEQ + (size_t)(nt - 8) * 256 * SEQ + sbase;
#pragma unroll
    for (int k = 0; k < 8; ++k) {
        int idx = tid + 512 * k;                 // 0..4095
        int d = idx >> 4, sg = idx & 15;
        uint4 v = *(const uint4*)&sm.T[d * 128 + ((sg * 8) ^ ((d & 7) << 3))];
        *(uint4*)(Vb + (size_t)d * SEQ + sg * 8) = v;
    }
}

// ------- scores + fused causal softmax -------------------------------------
// Compact triangular grid (136 jobs/batch). After writing its S tile, each
// block of strip (z,ym): threadfence -> atomicAdd(release) on the strip
// counter -> spin(acquire) until all ym+1 blocks arrived -> softmax its
// 1/(ym+1) share of the strip's 128 rows (wave-parallel, shfl-only).
// Residency proof (spin-safe): 544 blocks < 768 co-resident slots
// (__launch_bounds__(256,3): 3 blocks/CU x 256 CUs), GPU idle at launch.
// Counters: 64 ints in a dead hole of S (batch 0, row 0, cols>=1024;
// row-0 valid/zero-fill region ends at col Z=128), memset after qkv.
__global__ __launch_bounds__(256, 3) void scores_sm(
    const u16* __restrict__ Q, const u16* __restrict__ K, u16* __restrict__ S,
    float scale, int* __restrict__ cnt) {
    // decode job j -> (ym, xn) with T(ym)=ym(ym+1)/2 <= j < T(ym+1)
    const int j = blockIdx.x;                      // 0..135
    int ym = (int)((sqrtf(8.f * (float)j + 1.f) - 1.f) * 0.5f);
    while ((ym + 1) * (ym + 2) / 2 <= j) ++ym;     // float-error fixup
    while (ym * (ym + 1) / 2 > j) --ym;
    const int xn = j - ym * (ym + 1) / 2;          // 0..ym

    __shared__ u16 lsA[128 * 64];   // 16 KB
    __shared__ u16 lsB[128 * 64];   // 16 KB
    const int tid = threadIdx.x;
    const int wave = tid >> 6, lane = tid & 63;
    const int quad = lane >> 4, l15 = lane & 15;
    const int wm = (wave >> 1) * 64, wn = (wave & 1) * 64;
    const int z = blockIdx.z;

    const u16* Ab = Q + (size_t)z * SEQ * DIM + (size_t)ym * 128 * DIM;
    const u16* Bb = K + (size_t)z * SEQ * DIM + (size_t)xn * 128 * DIM;
    floatx4 acc[4][4];
    mainloop(Ab, Bb, DIM, DIM, DIM, lsA, lsB,
             tid, wave, quad, l15, wm, wn, acc);

    u16* Sz = S + (size_t)z * SEQ * SEQ;
    const int m0 = ym * 128 + wm + quad * 4;
    const int n0 = xn * 128 + wn + l15;
#pragma unroll
    for (int jj = 0; jj < 4; jj++)
#pragma unroll
        for (int i = 0; i < 4; i++)
#pragma unroll
            for (int r = 0; r < 4; r++)
                Sz[(size_t)(m0 + i * 16 + r) * SEQ + (n0 + jj * 16)] = f2bf(acc[i][jj][r] * scale);

    // ---- strip rendezvous (device-scope) ----
    __threadfence();
    __syncthreads();
    const int ci = z * 16 + ym;
    if (tid == 0) {
        __hip_atomic_fetch_add(&cnt[ci], 1, __ATOMIC_RELEASE, __HIP_MEMORY_SCOPE_AGENT);
        while (__hip_atomic_load(&cnt[ci], __ATOMIC_ACQUIRE, __HIP_MEMORY_SCOPE_AGENT) < ym + 1)
            __builtin_amdgcn_s_sleep(2);
    }
    __syncthreads();
    __threadfence();   // block-wide acquire: invalidate caches

    // ---- softmax slice: rows r = xn + t*(ym+1), t handled round-robin by wave
    const int Zs = (ym + 1) * 128;
    const int period = ym + 1;
    u16* Srow0 = Sz + (size_t)ym * 128 * SEQ;
    const int c0 = lane * 8;
    for (int t = wave; ; t += 4) {
        const int r = xn + t * period;
        if (r >= 128) break;
        const int L = ym * 128 + r + 1;            // valid keys for row q
        u16* prow = Srow0 + (size_t)r * SEQ;
        float f[4][8];
        bool act[4];
        float mx = -3.0e38f;
#pragma unroll
        for (int u = 0; u < 4; ++u) {
            const int cb = c0 + 512 * u;
            act[u] = cb < Zs;
            if (act[u]) {
                uint4 rv = *(const uint4*)(prow + cb);
                unsigned wv[4] = {rv.x, rv.y, rv.z, rv.w};
#pragma unroll
                for (int e = 0; e < 8; ++e) {
                    u16 h = (u16)((wv[e >> 1] >> ((e & 1) * 16)) & 0xFFFFu);
                    f[u][e] = (cb + e < L) ? bf2f(h) : -3.0e38f;
                    mx = fmaxf(mx, f[u][e]);
                }
            }
        }
#pragma unroll
        for (int o = 32; o > 0; o >>= 1) mx = fmaxf(mx, __shfl_xor(mx, o));
        float s = 0.f;
#pragma unroll
        for (int u = 0; u < 4; ++u)
            if (act[u]) {
#pragma unroll
                for (int e = 0; e < 8; ++e) {
                    float pe = (f[u][e] > -1.0e38f) ? __expf(f[u][e] - mx) : 0.f;
                    f[u][e] = pe;
                    s += pe;
                }
            }
#pragma unroll
        for (int o = 32; o > 0; o >>= 1) s += __shfl_xor(s, o);
        const float inv = 1.0f / s;
#pragma unroll
        for (int u = 0; u < 4; ++u)
            if (act[u]) {
                unsigned o2[4];
#pragma unroll
                for (int e = 0; e < 4; ++e) {
                    unsigned lo = f2bf(f[u][2 * e] * inv);
                    unsigned hi = f2bf(f[u][2 * e + 1] * inv);
                    o2[e] = lo | (hi << 16);
                }
                uint4 ov = {o2[0], o2[1], o2[2], o2[3]};
                *(uint4*)(prow + c0 + 512 * u) = ov;
            }
    }
}

// ------- context: out = P @ Vt^T (128x128, K limited) ----------------------
// Complementary-ym pairing keeps per-CU work uniform.
__global__ __launch_bounds__(256, 3) void gemm_pv(
    const u16* __restrict__ P, const u16* __restrict__ Vt, float* __restrict__ O) {
    const int ym = (blockIdx.z & 2) ? (int)blockIdx.y : (15 - (int)blockIdx.y);
    __shared__ u16 lsA[128 * 64];
    __shared__ u16 lsB[128 * 64];
    const int tid = threadIdx.x;
    const int wave = tid >> 6, lane = tid & 63;
    const int quad = lane >> 4, l15 = lane & 15;
    const int wm = (wave >> 1) * 64, wn = (wave & 1) * 64;
    const int z = blockIdx.z;

    const u16* Ab = P + (size_t)z * SEQ * SEQ + (size_t)ym * 128 * SEQ;
    const u16* Bb = Vt + (size_t)z * DIM * SEQ + (size_t)blockIdx.x * 128 * SEQ;
    const int Kt = (ym + 1) * 128;  // keys needed by rows ym*128..+127
    floatx4 acc[4][4];
    mainloop(Ab, Bb, SEQ, SEQ, Kt, lsA, lsB,
             tid, wave, quad, l15, wm, wn, acc);

    float* Cf = O + (size_t)z * SEQ * DIM;
    const int m0 = ym * 128 + wm + quad * 4;
    const int n0 = blockIdx.x * 128 + wn + l15;
#pragma unroll
    for (int j = 0; j < 4; j++)
#pragma unroll
        for (int i = 0; i < 4; i++)
#pragma unroll
            for (int r = 0; r < 4; r++)
                Cf[(size_t)(m0 + i * 16 + r) * DIM + (n0 + j * 16)] = acc[i][j][r];
}

extern "C" void kernel_launch(void* const* d_in, const int* in_sizes, int n_in,
                              void* d_out, int out_size, void* d_ws, size_t ws_size,
                              hipStream_t stream) {
    const float* x = (const float*)d_in[0];
    const float* Wq = (const float*)d_in[1];
    const float* bq = (const float*)d_in[2];
    const float* Wk = (const float*)d_in[3];
    const float* bk = (const float*)d_in[4];
    const float* Wv = (const float*)d_in[5];
    const float* bv = (const float*)d_in[6];
    float* out = (float*)d_out;

    char* ws = (char*)d_ws;
    const size_t MB = 1024ull * 1024ull;
    // layout: [0,32MB) early: xb(16MB)+Wt(6MB); late: S/P bf16 (32MB)
    //         [32,48) Q bf16 ; [48,64) K bf16 ; [64,80) Vt bf16 [d][s] per batch
    // counters: 256 B inside S batch 0 row 0 cols 1024.. (dead: Z=128 for row 0)
    u16* S = (u16*)ws;
    u16* xb = (u16*)ws;
    u16* Wt = (u16*)(ws + 16 * MB);
    u16* QK = (u16*)(ws + 32 * MB);
    u16* Vt = (u16*)(ws + 64 * MB);
    int* cnt = (int*)(ws + 2048);               // 64 x int, within dead S hole
    const size_t MAT = (size_t)B_ * SEQ * DIM;  // 8M elements
    u16* Q = QK;
    u16* Km = QK + MAT;

    const float scale = 0.03125f;  // 1/sqrt(1024)

    prep<<<8960, 256, 0, stream>>>((const float4*)x, (ushort4*)xb, Wq, Wk, Wv, Wt);
    gemm_qkv_r3<<<dim3(768), dim3(512), 0, stream>>>(xb, Wt, QK, bq, bk, bv, Vt);
    // zero strip counters AFTER qkv (the hole overlaps xb, which qkv reads)
    hipMemsetAsync(cnt, 0, 256, stream);
    scores_sm<<<dim3(136, 1, 4), 256, 0, stream>>>(Q, Km, S, scale, cnt);
    gemm_pv<<<dim3(8, 16, 4), 256, 0, stream>>>(S, Vt, out);
}

// Round 8
// 250.306 us; speedup vs baseline: 1.7369x; 1.7369x over previous
//
#include <hip/hip_runtime.h>

typedef unsigned short u16;
typedef __bf16 bf16x8 __attribute__((ext_vector_type(8)));
typedef float floatx4 __attribute__((ext_vector_type(4)));

#define B_ 4
#define SEQ 2048
#define DIM 1024

__device__ __forceinline__ u16 f2bf(float f) {
    unsigned u = __builtin_bit_cast(unsigned, f);
    u += 0x7FFFu + ((u >> 16) & 1u);
    return (u16)(u >> 16);
}
__device__ __forceinline__ float bf2f(u16 h) {
    unsigned u = ((unsigned)h) << 16;
    return __builtin_bit_cast(float, u);
}

#define GPTR(p) ((const __attribute__((address_space(1))) void*)(p))
#define LPTR(p) ((__attribute__((address_space(3))) void*)(p))
#define GLD(src, dstp) __builtin_amdgcn_global_load_lds(GPTR(src), LPTR(dstp), 16, 0, 0)

// ------------- prep: convert x fp32->bf16  +  transpose W fp32->Wt bf16 -----
// Fused (independent work): blocks [0,8192) convert, [8192,8960) transpose.
__global__ __launch_bounds__(256) void prep(
    const float4* __restrict__ x, ushort4* __restrict__ xb,
    const float* __restrict__ Wq, const float* __restrict__ Wk,
    const float* __restrict__ Wv, u16* __restrict__ Wt) {
    const int bx = blockIdx.x, tid = threadIdx.x;
    if (bx < 8192) {
        int i = bx * 256 + tid;  // 2M float4s
        float4 v = x[i];
        ushort4 o;
        o.x = f2bf(v.x); o.y = f2bf(v.y); o.z = f2bf(v.z); o.w = f2bf(v.w);
        xb[i] = o;
        return;
    }
    __shared__ u16 t[64][66];
    const int b = bx - 8192;               // 0..767
    const int kx = b & 15, ny = (b >> 4) & 15, z = b >> 8;
    const float* W = (z == 0) ? Wq : ((z == 1) ? Wk : Wv);
    u16* out = Wt + (size_t)z * DIM * DIM;
    const int tx = tid & 31, ty = tid >> 5;   // (32,8)
    const int k0 = kx * 64, n0 = ny * 64;
#pragma unroll
    for (int j = 0; j < 8; j++) {
        int k = ty + 8 * j;
        float2 v = *(const float2*)(W + (size_t)(k0 + k) * DIM + n0 + 2 * tx);
        t[2 * tx][k] = f2bf(v.x);
        t[2 * tx + 1][k] = f2bf(v.y);
    }
    __syncthreads();
#pragma unroll
    for (int j = 0; j < 8; j++) {
        int n = ty + 8 * j;
        ushort2 o;
        o.x = t[n][2 * tx];
        o.y = t[n][2 * tx + 1];
        *(ushort2*)(out + (size_t)(n0 + n) * DIM + k0 + 2 * tx) = o;
    }
}

// ---- 128x128 bf16 MFMA mainloop (used by scores/pv) -----------------------
__device__ __forceinline__ void mainloop(
    const u16* __restrict__ Ab, const u16* __restrict__ Bb, int lda, int ldb,
    int Kt, u16* lsA, u16* lsB, int tid, int wave, int quad, int l15,
    int wm, int wn, floatx4 (&acc)[4][4]) {
    const int srow = tid >> 2;                                // 0..63
    const int scol = ((tid & 3) ^ ((tid >> 3) & 3)) * 8;      // swizzled kseg
    const u16* gA = Ab + (size_t)srow * lda + scol;
    const u16* gB = Bb + (size_t)srow * ldb + scol;
    const int swq = (quad ^ ((l15 >> 1) & 3)) * 8;            // read-side xor

#pragma unroll
    for (int i = 0; i < 4; i++)
#pragma unroll
        for (int j = 0; j < 4; j++) {
            floatx4 zz = {0.f, 0.f, 0.f, 0.f};
            acc[i][j] = zz;
        }

    for (int k0 = 0; k0 < Kt; k0 += 64) {
#pragma unroll
        for (int h = 0; h < 2; h++)
#pragma unroll
            for (int c = 0; c < 2; c++) {
                __builtin_amdgcn_global_load_lds(
                    GPTR(gA + (size_t)c * 64 * lda + h * 32),
                    LPTR(lsA + h * 4096 + c * 2048 + wave * 512), 16, 0, 0);
                __builtin_amdgcn_global_load_lds(
                    GPTR(gB + (size_t)c * 64 * ldb + h * 32),
                    LPTR(lsB + h * 4096 + c * 2048 + wave * 512), 16, 0, 0);
            }
        gA += 64; gB += 64;
        __syncthreads();

#pragma unroll
        for (int h = 0; h < 2; h++) {
            bf16x8 af[4];
#pragma unroll
            for (int i = 0; i < 4; i++)
                af[i] = *(const bf16x8*)(lsA + h * 4096 + (wm + i * 16 + l15) * 32 + swq);
#pragma unroll
            for (int j = 0; j < 4; j++) {
                bf16x8 bfr = *(const bf16x8*)(lsB + h * 4096 + (wn + j * 16 + l15) * 32 + swq);
#pragma unroll
                for (int i = 0; i < 4; i++)
                    acc[i][j] = __builtin_amdgcn_mfma_f32_16x16x32_bf16(af[i], bfr, acc[i][j], 0, 0, 0);
            }
        }
        __syncthreads();
    }
}

// ========== QKV projection: 128x256 tile, BK=64, ring-3 LDS, 1 barrier/tile =
// (verified rounds 3+4: 63-64 µs, MfmaUtil 33%, no spill) — r3 verbatim.
__global__ __launch_bounds__(512, 2) void gemm_qkv_r3(
    const u16* __restrict__ A, const u16* __restrict__ Bt, u16* __restrict__ QK,
    const float* __restrict__ b0, const float* __restrict__ b1,
    const float* __restrict__ b2, u16* __restrict__ VtOut) {
    __shared__ union {
        u16 stage[3][24576];   // 3 x (A 16KB + B 32KB) = 144 KiB
        u16 T[256 * 128];      // V^T transpose staging (64 KB)
    } sm;

    const int tid = threadIdx.x;
    const int wave = tid >> 6, lane = tid & 63;
    const int quad = lane >> 4, l15 = lane & 15;
    const int wm = (wave >> 2) * 64;   // 2 M-waves
    const int wn = (wave & 3) * 64;    // 4 N-waves
    const int wl = wave * 512;         // wave-uniform LDS chunk (u16)

    // XCD-bijective swizzle: 768 = 8 * 96; mt-fast (B-panel L2 reuse)
    const int bid = blockIdx.x;
    const int wgid = (bid & 7) * 96 + (bid >> 3);
    const int mt = wgid & 63, nt = wgid >> 6;   // 64 M-tiles x 12 N-tiles

    // staging: thread t covers row t>>3 (of 64), slot t&7; src seg pre-swizzled
    const int srow = tid >> 3;
    const int sseg = (tid & 7) ^ (srow & 7);
    const u16* gA = A + (size_t)(mt * 128 + srow) * DIM + sseg * 8;
    const u16* gB = Bt + (size_t)(nt * 256 + srow) * DIM + sseg * 8;

    u16* p0 = &sm.stage[0][0];
    u16* p1 = &sm.stage[1][0];
    u16* p2 = &sm.stage[2][0];

    const int s0 = (quad ^ (l15 & 7)) * 8;      // ks=0 slot; ks=1 = s0 ^ 32
    const int rAoff = (wm + l15) * 64;
    const int rBoff = 8192 + (wn + l15) * 64;

    floatx4 acc[4][4];
#pragma unroll
    for (int i = 0; i < 4; i++)
#pragma unroll
        for (int j = 0; j < 4; j++) {
            floatx4 zz = {0.f, 0.f, 0.f, 0.f};
            acc[i][j] = zz;
        }

#define QKV_STAGE(bW) do { \
    GLD(gA,                      (bW) + wl); \
    GLD(gA + (size_t)64 * DIM,   (bW) + 4096 + wl); \
    GLD(gB,                      (bW) + 8192 + wl); \
    GLD(gB + (size_t)64 * DIM,   (bW) + 12288 + wl); \
    GLD(gB + (size_t)128 * DIM,  (bW) + 16384 + wl); \
    GLD(gB + (size_t)192 * DIM,  (bW) + 20480 + wl); \
    gA += 64; gB += 64; } while (0)

#define QKV_TILE(bR, bW, STG, EVM) do { \
    __builtin_amdgcn_s_barrier(); \
    if (STG) QKV_STAGE(bW); \
    const u16* rA_ = (bR) + rAoff; \
    const u16* rB_ = (bR) + rBoff; \
    bf16x8 a_[4], bv_[4]; \
    _Pragma("unroll") for (int i_ = 0; i_ < 4; ++i_) a_[i_] = *(const bf16x8*)(rA_ + i_ * 1024 + s0); \
    _Pragma("unroll") for (int j_ = 0; j_ < 4; ++j_) bv_[j_] = *(const bf16x8*)(rB_ + j_ * 1024 + s0); \
    __builtin_amdgcn_s_setprio(1); \
    _Pragma("unroll") for (int j_ = 0; j_ < 4; ++j_) \
    _Pragma("unroll") for (int i_ = 0; i_ < 4; ++i_) \
        acc[i_][j_] = __builtin_amdgcn_mfma_f32_16x16x32_bf16(a_[i_], bv_[j_], acc[i_][j_], 0, 0, 0); \
    __builtin_amdgcn_s_setprio(0); \
    _Pragma("unroll") for (int i_ = 0; i_ < 4; ++i_) a_[i_] = *(const bf16x8*)(rA_ + i_ * 1024 + (s0 ^ 32)); \
    _Pragma("unroll") for (int j_ = 0; j_ < 4; ++j_) bv_[j_] = *(const bf16x8*)(rB_ + j_ * 1024 + (s0 ^ 32)); \
    __builtin_amdgcn_s_setprio(1); \
    _Pragma("unroll") for (int j_ = 0; j_ < 4; ++j_) \
    _Pragma("unroll") for (int i_ = 0; i_ < 4; ++i_) \
        acc[i_][j_] = __builtin_amdgcn_mfma_f32_16x16x32_bf16(a_[i_], bv_[j_], acc[i_][j_], 0, 0, 0); \
    __builtin_amdgcn_s_setprio(0); \
    if ((EVM) == 6) { asm volatile("s_waitcnt vmcnt(6)" ::: "memory"); } \
    else if ((EVM) == 0) { asm volatile("s_waitcnt vmcnt(0)" ::: "memory"); } \
    } while (0)

    // prologue: stage tiles 0,1; force tile 0 landed (6 newest = tile 1 float)
    QKV_STAGE(p0);
    QKV_STAGE(p1);
    asm volatile("s_waitcnt vmcnt(6)" ::: "memory");

    for (int tt = 0; tt < 4; ++tt) {   // T = 0..11
        QKV_TILE(p0, p2, 1, 6);
        QKV_TILE(p1, p0, 1, 6);
        QKV_TILE(p2, p1, 1, 6);
    }
    QKV_TILE(p0, p2, 1, 6);    // T=12 (stages tile 14)
    QKV_TILE(p1, p0, 1, 6);    // T=13 (stages tile 15; forces 14)
    QKV_TILE(p2, p1, 0, 0);    // T=14 (tail drain: forces 15)
    QKV_TILE(p0, p1, 0, -1);   // T=15

#undef QKV_TILE
#undef QKV_STAGE

    // ---------------- epilogue ----------------
    const int z = nt >> 2;                          // 0=Q 1=K 2=V
    const int nc = (nt & 3) * 256 + wn + l15;       // col within z-matrix (+j*16)
    const float* bias = (z == 0) ? b0 : ((z == 1) ? b1 : b2);

    if (z < 2) {
        u16* Cb = QK + (size_t)z * B_ * SEQ * DIM;
        const int m00 = mt * 128 + wm + quad * 4;
#pragma unroll
        for (int j = 0; j < 4; ++j) {
            float bv2 = bias[nc + j * 16];
#pragma unroll
            for (int i = 0; i < 4; ++i)
#pragma unroll
                for (int r = 0; r < 4; ++r)
                    Cb[(size_t)(m00 + i * 16 + r) * DIM + nc + j * 16] =
                        f2bf(acc[i][j][r] + bv2);
        }
        return;
    }

    // z == 2: V^T [d][s] via LDS transpose (token-XOR swizzle kills the
    // 256B-stride conflict; XOR in 8-token units keeps 8B writes/16B reads ok)
    float addj[4];
#pragma unroll
    for (int j = 0; j < 4; ++j) addj[j] = bias[nc + j * 16];
    __syncthreads();                 // all waves done with stage LDS
#pragma unroll
    for (int i = 0; i < 4; ++i) {
        const int tb = wm + i * 16 + quad * 4;       // token base 0..127 (x4)
#pragma unroll
        for (int j = 0; j < 4; ++j) {
            const int d = wn + j * 16 + l15;         // local dim 0..255
            ushort4 o;
            o.x = f2bf(acc[i][j][0] + addj[j]);
            o.y = f2bf(acc[i][j][1] + addj[j]);
            o.z = f2bf(acc[i][j][2] + addj[j]);
            o.w = f2bf(acc[i][j][3] + addj[j]);
            *(ushort4*)&sm.T[d * 128 + (tb ^ ((d & 7) << 3))] = o;
        }
    }
    __syncthreads();
    const int bI = mt >> 4;
    const int sbase = (mt & 15) * 128;
    u16* Vb = VtOut + (size_t)bI * DIM * SEQ + (size_t)(nt - 8) * 256 * SEQ + sbase;
#pragma unroll
    for (int k = 0; k < 8; ++k) {
        int idx = tid + 512 * k;                 // 0..4095
        int d = idx >> 4, sg = idx & 15;
        uint4 v = *(const uint4*)&sm.T[d * 128 + ((sg * 8) ^ ((d & 7) << 3))];
        *(uint4*)(Vb + (size_t)d * SEQ + sg * 8) = v;
    }
}

// ------- scores: S = Q @ K^T * scale --------------------------------------
// Compact triangular grid: 136 active jobs/batch (x <= ym), 544 blocks total.
__global__ __launch_bounds__(256, 3) void gemm_scores(
    const u16* __restrict__ Q, const u16* __restrict__ K, u16* __restrict__ S,
    float scale) {
    // decode job j -> (ym, xn) with T(ym)=ym(ym+1)/2 <= j < T(ym+1)
    const int j = blockIdx.x;                      // 0..135
    int ym = (int)((sqrtf(8.f * (float)j + 1.f) - 1.f) * 0.5f);
    while ((ym + 1) * (ym + 2) / 2 <= j) ++ym;     // float-error fixup
    while (ym * (ym + 1) / 2 > j) --ym;
    const int xn = j - ym * (ym + 1) / 2;          // 0..ym

    __shared__ u16 lsA[128 * 64];   // 16 KB
    __shared__ u16 lsB[128 * 64];   // 16 KB
    const int tid = threadIdx.x;
    const int wave = tid >> 6, lane = tid & 63;
    const int quad = lane >> 4, l15 = lane & 15;
    const int wm = (wave >> 1) * 64, wn = (wave & 1) * 64;
    const int z = blockIdx.z;

    const u16* Ab = Q + (size_t)z * SEQ * DIM + (size_t)ym * 128 * DIM;
    const u16* Bb = K + (size_t)z * SEQ * DIM + (size_t)xn * 128 * DIM;
    floatx4 acc[4][4];
    mainloop(Ab, Bb, DIM, DIM, DIM, lsA, lsB,
             tid, wave, quad, l15, wm, wn, acc);

    u16* Cb = S + (size_t)z * SEQ * SEQ;
    const int m0 = ym * 128 + wm + quad * 4;
    const int n0 = xn * 128 + wn + l15;
#pragma unroll
    for (int jj = 0; jj < 4; jj++)
#pragma unroll
        for (int i = 0; i < 4; i++)
#pragma unroll
            for (int r = 0; r < 4; r++)
                Cb[(size_t)(m0 + i * 16 + r) * SEQ + (n0 + jj * 16)] = f2bf(acc[i][jj][r] * scale);
}

// ------- context: out = P @ Vt^T (128x128, K limited) ----------------------
// Complementary-ym pairing keeps per-CU work uniform.
__global__ __launch_bounds__(256, 3) void gemm_pv(
    const u16* __restrict__ P, const u16* __restrict__ Vt, float* __restrict__ O) {
    const int ym = (blockIdx.z & 2) ? (int)blockIdx.y : (15 - (int)blockIdx.y);
    __shared__ u16 lsA[128 * 64];
    __shared__ u16 lsB[128 * 64];
    const int tid = threadIdx.x;
    const int wave = tid >> 6, lane = tid & 63;
    const int quad = lane >> 4, l15 = lane & 15;
    const int wm = (wave >> 1) * 64, wn = (wave & 1) * 64;
    const int z = blockIdx.z;

    const u16* Ab = P + (size_t)z * SEQ * SEQ + (size_t)ym * 128 * SEQ;
    const u16* Bb = Vt + (size_t)z * DIM * SEQ + (size_t)blockIdx.x * 128 * SEQ;
    const int Kt = (ym + 1) * 128;  // keys needed by rows ym*128..+127
    floatx4 acc[4][4];
    mainloop(Ab, Bb, SEQ, SEQ, Kt, lsA, lsB,
             tid, wave, quad, l15, wm, wn, acc);

    float* Cf = O + (size_t)z * SEQ * DIM;
    const int m0 = ym * 128 + wm + quad * 4;
    const int n0 = blockIdx.x * 128 + wn + l15;
#pragma unroll
    for (int j = 0; j < 4; j++)
#pragma unroll
        for (int i = 0; i < 4; i++)
#pragma unroll
            for (int r = 0; r < 4; r++)
                Cf[(size_t)(m0 + i * 16 + r) * DIM + (n0 + j * 16)] = acc[i][j][r];
}

// -------- causal softmax: one row per block, register-resident, 1R+1W --------
__global__ __launch_bounds__(256) void softmax_causal(u16* __restrict__ S) {
    const int q = blockIdx.x, b = blockIdx.y, tid = threadIdx.x;
    u16* row = S + ((size_t)b * SEQ + q) * SEQ;
    const int L = q + 1;                    // valid keys
    const int Z = ((q >> 7) + 1) << 7;      // zero-fill bound = PV's K_eff
    const int k0 = tid * 8;
    __shared__ float redm[4], reds[4];

    uint4 rv = ((const uint4*)row)[tid];
    unsigned w[4] = {rv.x, rv.y, rv.z, rv.w};
    float f[8];
#pragma unroll
    for (int e = 0; e < 8; e++) {
        u16 h = (u16)((w[e >> 1] >> ((e & 1) * 16)) & 0xFFFFu);
        f[e] = (k0 + e < L) ? bf2f(h) : -3.0e38f;
    }
    float m = f[0];
#pragma unroll
    for (int e = 1; e < 8; e++) m = fmaxf(m, f[e]);
#pragma unroll
    for (int o = 32; o > 0; o >>= 1) m = fmaxf(m, __shfl_xor(m, o));
    if ((tid & 63) == 0) redm[tid >> 6] = m;
    __syncthreads();
    m = fmaxf(fmaxf(redm[0], redm[1]), fmaxf(redm[2], redm[3]));

    float p[8];
    float s = 0.f;
#pragma unroll
    for (int e = 0; e < 8; e++) {
        p[e] = (k0 + e < L) ? __expf(f[e] - m) : 0.f;
        s += p[e];
    }
#pragma unroll
    for (int o = 32; o > 0; o >>= 1) s += __shfl_xor(s, o);
    if ((tid & 63) == 0) reds[tid >> 6] = s;
    __syncthreads();
    s = reds[0] + reds[1] + reds[2] + reds[3];
    const float inv = 1.0f / s;

    if (k0 < Z) {
        unsigned o2[4];
#pragma unroll
        for (int e = 0; e < 4; e++) {
            unsigned lo = f2bf(p[2 * e] * inv);
            unsigned hi = f2bf(p[2 * e + 1] * inv);
            o2[e] = lo | (hi << 16);
        }
        uint4 ov = {o2[0], o2[1], o2[2], o2[3]};
        ((uint4*)row)[tid] = ov;
    }
}

extern "C" void kernel_launch(void* const* d_in, const int* in_sizes, int n_in,
                              void* d_out, int out_size, void* d_ws, size_t ws_size,
                              hipStream_t stream) {
    const float* x = (const float*)d_in[0];
    const float* Wq = (const float*)d_in[1];
    const float* bq = (const float*)d_in[2];
    const float* Wk = (const float*)d_in[3];
    const float* bk = (const float*)d_in[4];
    const float* Wv = (const float*)d_in[5];
    const float* bv = (const float*)d_in[6];
    float* out = (float*)d_out;

    char* ws = (char*)d_ws;
    const size_t MB = 1024ull * 1024ull;
    // layout: [0,32MB) early: xb(16MB)+Wt(6MB); late: S/P bf16 (32MB)
    //         [32,48) Q bf16 ; [48,64) K bf16 ; [64,80) Vt bf16 [d][s] per batch
    u16* S = (u16*)ws;
    u16* xb = (u16*)ws;
    u16* Wt = (u16*)(ws + 16 * MB);
    u16* QK = (u16*)(ws + 32 * MB);
    u16* Vt = (u16*)(ws + 64 * MB);
    const size_t MAT = (size_t)B_ * SEQ * DIM;  // 8M elements
    u16* Q = QK;
    u16* Km = QK + MAT;

    const float scale = 0.03125f;  // 1/sqrt(1024)

    prep<<<8960, 256, 0, stream>>>((const float4*)x, (ushort4*)xb, Wq, Wk, Wv, Wt);
    gemm_qkv_r3<<<dim3(768), dim3(512), 0, stream>>>(xb, Wt, QK, bq, bk, bv, Vt);
    gemm_scores<<<dim3(136, 1, 4), 256, 0, stream>>>(Q, Km, S, scale);
    softmax_causal<<<dim3(SEQ, B_), 256, 0, stream>>>(S);
    gemm_pv<<<dim3(8, 16, 4), 256, 0, stream>>>(S, Vt, out);
}